// Round 12
// baseline (525.678 us; speedup 1.0000x reference)
//
#include <hip/hip_runtime.h>
#include <hip/hip_bf16.h>
#include <cstdint>

#define P_ 88   // pitches (sequence length of the scan)
#define B_ 16   // batch
#define T_ 256  // timesteps (folded into batch N)
#define H_ 188  // per-pitch features
#define G_ 192  // 4*48 gates; also LSTM1 input size (188 feat + 4 ctx)
#define U_ 48   // LSTM units
#define N_ 4096 // B_*T_

typedef __attribute__((ext_vector_type(8))) short bf16x8;
typedef __attribute__((ext_vector_type(8))) _Float16 f16x8;
typedef __attribute__((ext_vector_type(4))) float f32x4;

__device__ __forceinline__ float sigf(float x) {
  return __builtin_amdgcn_rcpf(1.0f + __expf(-x));
}
__device__ __forceinline__ float tanh_f(float x) {
  return 1.0f - 2.0f * __builtin_amdgcn_rcpf(1.0f + __expf(2.0f * x));
}
__device__ __forceinline__ unsigned short f2bs(float v) {
  union { __hip_bfloat16 h; unsigned short s; } u;
  u.h = __float2bfloat16(v);
  return u.s;
}
__device__ __forceinline__ float bs2f(unsigned short s) {
  union { unsigned int u; float f; } x;
  x.u = ((unsigned int)s) << 16;
  return x.f;
}
__device__ __forceinline__ float hs2f(unsigned short s) {
  union { unsigned short u; _Float16 h; } x;
  x.u = s;
  return (float)x.h;
}
__device__ __forceinline__ unsigned short f2hs(float v) {
  union { _Float16 h; unsigned short s; } x;
  x.h = (_Float16)v;
  return x.s;
}
// truncation-based hi/lo bf16 split (hi+lo == h to ~2^-17)
__device__ __forceinline__ void hsplit(float h, unsigned short& hi, unsigned short& lo) {
  union { float f; unsigned int u; } x;
  x.f = h;
  hi = (unsigned short)(x.u >> 16);
  union { float f; unsigned int u; } y;
  y.f = h - bs2f(hi);
  lo = (unsigned short)(y.u >> 16);
}

// Relaxed workgroup barrier: waits only on LDS ops (lgkmcnt), NOT vmcnt.
__device__ __forceinline__ void lds_barrier() {
  asm volatile("s_waitcnt lgkmcnt(0)\n\ts_barrier" ::: "memory");
}

// ---------------------------------------------------------------------------
// Kernel 1: context MLP -> per-(b,p) gate bias vector
// ---------------------------------------------------------------------------
__global__ void ctx_kernel(const float* __restrict__ pc,
                           const float* __restrict__ fc1w, const float* __restrict__ fc1b,
                           const float* __restrict__ fc2w, const float* __restrict__ fc2b,
                           const float* __restrict__ fc3w, const float* __restrict__ fc3b,
                           const float* __restrict__ wih1,
                           const float* __restrict__ bih1, const float* __restrict__ bhh1,
                           float* __restrict__ ctxg) {
  int bp = blockIdx.x * 64 + threadIdx.x;
  if (bp >= B_ * P_) return;
  float p0 = pc[bp * 3 + 0], p1 = pc[bp * 3 + 1], p2 = pc[bp * 3 + 2];
  float x1[16], x2[16];
#pragma unroll
  for (int jj = 0; jj < 16; ++jj)
    x1[jj] = fmaxf(0.f, fc1w[jj * 3 + 0] * p0 + fc1w[jj * 3 + 1] * p1 + fc1w[jj * 3 + 2] * p2 + fc1b[jj]);
#pragma unroll
  for (int jj = 0; jj < 16; ++jj) {
    float s = fc2b[jj];
#pragma unroll
    for (int i = 0; i < 16; ++i) s += fc2w[jj * 16 + i] * x1[i];
    x2[jj] = fmaxf(0.f, s);
  }
  float ce[4];
#pragma unroll
  for (int jj = 0; jj < 4; ++jj) {
    float s = fc3b[jj];
#pragma unroll
    for (int i = 0; i < 16; ++i) s += fc3w[jj * 16 + i] * x2[i];
    ce[jj] = s;
  }
  float* op = ctxg + (size_t)bp * G_;
  for (int g = 0; g < G_; ++g) {
    const float* wr = wih1 + (size_t)g * G_ + H_;
    op[g] = bih1[g] + bhh1[g] + ce[0] * wr[0] + ce[1] * wr[1] + ce[2] * wr[2] + ce[3] * wr[3];
  }
}

// ---------------------------------------------------------------------------
// Kernel 1b: pack wih1 feature columns into f16 MFMA B-fragment order.
// ---------------------------------------------------------------------------
__global__ __launch_bounds__(256) void wfrag_kernel(const float* __restrict__ wih1,
                                                    f16x8* __restrict__ wfrag) {
  const int idx = blockIdx.x * 256 + threadIdx.x;
  if (idx >= 12 * 6 * 64) return;
  const int l = idx & 63;
  const int kc = (idx >> 6) % 6;
  const int j = idx / 384;
  const int g = j * 16 + (l & 15);
  const int k0 = kc * 32 + (l >> 4) * 8;
  f16x8 v;
#pragma unroll
  for (int e = 0; e < 8; ++e) {
    const int k = k0 + e;
    const float wv = (k < H_) ? wih1[(size_t)g * G_ + k] : 0.f;
    v[e] = (_Float16)wv;
  }
  wfrag[idx] = v;
}

// ---------------------------------------------------------------------------
// Kernel 2: MFMA GEMM with LDS-staged A and LDS-repacked stores (round 10).
// ---------------------------------------------------------------------------
__global__ __launch_bounds__(256, 3) void gemm_mfma(const float* __restrict__ pf,
                                                    const f16x8* __restrict__ wfrag,
                                                    const float* __restrict__ ctxg,
                                                    unsigned short* __restrict__ xg2) {
  const int bp = blockIdx.x >> 1, tb = blockIdx.x & 1;
  const int p = bp % P_, b = bp / P_;
  const int tid = threadIdx.x;
  const int w = tid >> 6, l = tid & 63;
  const int lj = l & 15, lq = l >> 4;

  __shared__ __align__(16) char ldsraw[49152];
  _Float16(*Ahi)[34] = (_Float16(*)[34])ldsraw;
  _Float16(*Alo)[34] = (_Float16(*)[34])(ldsraw + 8704);

  float cg[12];
#pragma unroll
  for (int jn = 0; jn < 12; ++jn)
    cg[jn] = ctxg[(size_t)bp * G_ + jn * 16 + lj];

  f32x4 acc[2][12];
#pragma unroll
  for (int mt = 0; mt < 2; ++mt)
#pragma unroll
    for (int jn = 0; jn < 12; ++jn)
#pragma unroll
      for (int r = 0; r < 4; ++r) acc[mt][jn][r] = 0.f;

  const float* Ab = pf + (size_t)bp * H_ * T_ + tb * 128;
  const int kl = tid >> 5;
  const int t4 = (tid & 31) * 4;

  for (int kc = 0; kc < 6; ++kc) {
    __syncthreads();
#pragma unroll
    for (int rr = 0; rr < 4; ++rr) {
      const int kk = rr * 8 + kl;
      const int kg = kc * 32 + kk;
      float a0 = 0.f, a1 = 0.f, a2 = 0.f, a3 = 0.f;
      if (kg < H_) {
        const float4 v = *(const float4*)(Ab + (size_t)kg * T_ + t4);
        a0 = v.x; a1 = v.y; a2 = v.z; a3 = v.w;
      }
      const _Float16 h0 = (_Float16)a0, h1 = (_Float16)a1;
      const _Float16 h2 = (_Float16)a2, h3 = (_Float16)a3;
      Ahi[t4 + 0][kk] = h0; Alo[t4 + 0][kk] = (_Float16)(a0 - (float)h0);
      Ahi[t4 + 1][kk] = h1; Alo[t4 + 1][kk] = (_Float16)(a1 - (float)h1);
      Ahi[t4 + 2][kk] = h2; Alo[t4 + 2][kk] = (_Float16)(a2 - (float)h2);
      Ahi[t4 + 3][kk] = h3; Alo[t4 + 3][kk] = (_Float16)(a3 - (float)h3);
    }
    __syncthreads();
    const int trow = w * 32;
    const f16x8 ahi0 = *(const f16x8*)&Ahi[trow + lj][lq * 8];
    const f16x8 ahi1 = *(const f16x8*)&Ahi[trow + 16 + lj][lq * 8];
    const f16x8 alo0 = *(const f16x8*)&Alo[trow + lj][lq * 8];
    const f16x8 alo1 = *(const f16x8*)&Alo[trow + 16 + lj][lq * 8];
#pragma unroll
    for (int jn = 0; jn < 12; ++jn) {
      const f16x8 wf = wfrag[(jn * 6 + kc) * 64 + l];
      acc[0][jn] = __builtin_amdgcn_mfma_f32_16x16x32_f16(ahi0, wf, acc[0][jn], 0, 0, 0);
      acc[1][jn] = __builtin_amdgcn_mfma_f32_16x16x32_f16(ahi1, wf, acc[1][jn], 0, 0, 0);
      acc[0][jn] = __builtin_amdgcn_mfma_f32_16x16x32_f16(alo0, wf, acc[0][jn], 0, 0, 0);
      acc[1][jn] = __builtin_amdgcn_mfma_f32_16x16x32_f16(alo1, wf, acc[1][jn], 0, 0, 0);
    }
  }
  __syncthreads();

  unsigned short* Cst = (unsigned short*)ldsraw + w * 6144;
#pragma unroll
  for (int mt = 0; mt < 2; ++mt)
#pragma unroll
    for (int jn = 0; jn < 12; ++jn)
#pragma unroll
      for (int r = 0; r < 4; ++r)
        Cst[mt * 3072 + jn * 256 + r * 64 + l] = f2hs(acc[mt][jn][r] + cg[jn]);
  const int nb0 = b * 16 + tb * 8 + w * 2;
  unsigned short* gb = xg2 + ((size_t)p * 256 + nb0) * 3072;
#pragma unroll
  for (int rr = 0; rr < 12; ++rr) {
    const uint4 v = *(const uint4*)(Cst + rr * 512 + l * 8);
    *(uint4*)(gb + rr * 512 + l * 8) = v;
  }
}

// ---------------------------------------------------------------------------
// Kernel 3: MFMA persistent scan, DUAL-GROUP ILP version.
// 256 blocks (1/CU) x 256 threads. Each block runs TWO independent 8-row
// scans X (rows n0..n0+7) and Y (n0+8..n0+15) in one instruction stream:
// every phase does X's and Y's work before the barrier, so X's LDS/MFMA
// latency is filled by Y's instructions (ILP — immune to the block-level
// convoy that made 2 blocks/CU useless in rounds 7-10).
// ---------------------------------------------------------------------------
__global__ __launch_bounds__(256, 1) void scan_mfma(
    const unsigned short* __restrict__ xg2,
    const float* __restrict__ whh1, const float* __restrict__ wih2,
    const float* __restrict__ whh2, const float* __restrict__ bih2,
    const float* __restrict__ bhh2, const float* __restrict__ fcw,
    const float* __restrict__ fcb, float* __restrict__ out) {
  __shared__ __align__(16) short hhX[16][104], hlX[16][104];
  __shared__ __align__(16) short hhY[16][104], hlY[16][104];
  __shared__ __align__(16) float gsX[8][196], gsY[8][196];
  __shared__ __align__(16) float h2fX[8][52], h2fY[8][52];
  __shared__ __align__(16) float fcws[5 * 48];
  __shared__ float logitX[5][8], probX[5][8];
  __shared__ float logitY[5][8], probY[5][8];

  const int tid = threadIdx.x;
  const int w = tid >> 6;
  const int l = tid & 63;
  const int lj = l & 15;
  const int lq = l >> 4;
  const int grp = blockIdx.x;
  const int n0 = grp * 16;
  const int b = n0 >> 8, t0 = n0 & 255;

  // ---- persistent weight B-fragments (round-10 mapping; shared X/Y) ----
  bf16x8 b1[3][2];
  bf16x8 b2f[3][3];
  float bias2r[3];
#pragma unroll
  for (int i = 0; i < 3; ++i) {
    const int j = w * 48 + i * 16 + lj;
    bias2r[i] = bih2[j] + bhh2[j];
#pragma unroll
    for (int kc = 0; kc < 2; ++kc)
#pragma unroll
      for (int e = 0; e < 8; ++e) {
        const int u = kc * 32 + lq * 8 + e;
        b1[i][kc][e] = (u < U_) ? (short)f2bs(whh1[j * U_ + u]) : (short)0;
      }
#pragma unroll
    for (int kc = 0; kc < 3; ++kc)
#pragma unroll
      for (int e = 0; e < 8; ++e) {
        const int u = kc * 32 + lq * 8 + e;
        b2f[i][kc][e] = (u < U_) ? (short)f2bs(wih2[j * U_ + u])
                                 : (short)f2bs(whh2[j * U_ + (u - U_)]);
      }
  }

  for (int e = tid; e < 16 * 104 / 2; e += 256) {
    ((unsigned int*)hhX)[e] = 0u; ((unsigned int*)hlX)[e] = 0u;
    ((unsigned int*)hhY)[e] = 0u; ((unsigned int*)hlY)[e] = 0u;
  }
  for (int e = tid; e < 5 * U_; e += 256) fcws[e] = fcw[e];

  // activation tasks: per group 384 = 8n x 48u; slot0 = tid, slot1 = 256+tid (tid<128)
  const int tn0 = tid / U_, tu0 = tid % U_;
  const int tn1 = (256 + tid) / U_, tu1 = (256 + tid) % U_;
  float c1X[2] = {0.f, 0.f}, c1Y[2] = {0.f, 0.f};
  float c2X[2] = {0.f, 0.f}, c2Y[2] = {0.f, 0.f};

  // aux roles: fc X: tid 0-39, fc Y: 40-79; store X: 96-135, Y: 136-175;
  // softmax X: 192-199, Y: 200-207.
  const bool fcXth = tid < 40, fcYth = tid >= 40 && tid < 80;
  const int fi = fcXth ? tid : (tid - 40);
  const int fk = fi >> 3, fn = fi & 7;
  const float fcbr = (fcXth || fcYth) ? fcb[fk] : 0.f;
  const bool stXth = tid >= 96 && tid < 136, stYth = tid >= 136 && tid < 176;
  const int si = stXth ? (tid - 96) : (tid - 136);
  const int sk = si >> 3, sn = si & 7;
  const bool smXth = tid >= 192 && tid < 200, smYth = tid >= 200 && tid < 208;
  const int smn = smXth ? (tid - 192) : (tid - 200);

  // xg prefetch for p=0; X = quads 0-1, Y = quads 2-3 of the 16-row group
  unsigned short xpX[12], xpY[12];
  {
    const size_t pb = (size_t)grp * 3072;
#pragma unroll
    for (int i = 0; i < 3; ++i)
#pragma unroll
      for (int r = 0; r < 4; ++r) {
        const size_t base = pb + (size_t)((w * 3 + i) * 256 + r * 64);
        xpX[i * 4 + r] = (lq < 2) ? xg2[base + lq * 16 + lj] : (unsigned short)0;
        xpY[i * 4 + r] = (lq < 2) ? xg2[base + (2 + lq) * 16 + lj] : (unsigned short)0;
      }
  }
  lds_barrier();

  for (int p = 0; p < P_; ++p) {
    // ======== PHASE A: L1 MFMA X+Y, issue p+1 prefetch | fc logits p-1 ========
    f32x4 cHX[3], cLX[3], cHY[3], cLY[3];
#pragma unroll
    for (int i = 0; i < 3; ++i)
#pragma unroll
      for (int r = 0; r < 4; ++r) {
        cHX[i][r] = hs2f(xpX[i * 4 + r]); cLX[i][r] = 0.f;
        cHY[i][r] = hs2f(xpY[i * 4 + r]); cLY[i][r] = 0.f;
      }
    if (p < P_ - 1) {
      const size_t pb = (size_t)((p + 1) * 256 + grp) * 3072;
#pragma unroll
      for (int i = 0; i < 3; ++i)
#pragma unroll
        for (int r = 0; r < 4; ++r) {
          const size_t base = pb + (size_t)((w * 3 + i) * 256 + r * 64);
          xpX[i * 4 + r] = (lq < 2) ? xg2[base + lq * 16 + lj] : (unsigned short)0;
          xpY[i * 4 + r] = (lq < 2) ? xg2[base + (2 + lq) * 16 + lj] : (unsigned short)0;
        }
    }
    {
      const short* hrX = &hhX[lj][0];
      const short* lrX = &hlX[lj][0];
      const short* hrY = &hhY[lj][0];
      const short* lrY = &hlY[lj][0];
      bf16x8 xa0 = *(const bf16x8*)(hrX + lq * 8);
      bf16x8 xa1 = *(const bf16x8*)(hrX + 32 + lq * 8);
      bf16x8 xl0 = *(const bf16x8*)(lrX + lq * 8);
      bf16x8 xl1 = *(const bf16x8*)(lrX + 32 + lq * 8);
      bf16x8 ya0 = *(const bf16x8*)(hrY + lq * 8);
      bf16x8 ya1 = *(const bf16x8*)(hrY + 32 + lq * 8);
      bf16x8 yl0 = *(const bf16x8*)(lrY + lq * 8);
      bf16x8 yl1 = *(const bf16x8*)(lrY + 32 + lq * 8);
#pragma unroll
      for (int i = 0; i < 3; ++i) {
        cHX[i] = __builtin_amdgcn_mfma_f32_16x16x32_bf16(xa0, b1[i][0], cHX[i], 0, 0, 0);
        cHY[i] = __builtin_amdgcn_mfma_f32_16x16x32_bf16(ya0, b1[i][0], cHY[i], 0, 0, 0);
      }
#pragma unroll
      for (int i = 0; i < 3; ++i) {
        cLX[i] = __builtin_amdgcn_mfma_f32_16x16x32_bf16(xl0, b1[i][0], cLX[i], 0, 0, 0);
        cLY[i] = __builtin_amdgcn_mfma_f32_16x16x32_bf16(yl0, b1[i][0], cLY[i], 0, 0, 0);
      }
#pragma unroll
      for (int i = 0; i < 3; ++i) {
        cHX[i] = __builtin_amdgcn_mfma_f32_16x16x32_bf16(xa1, b1[i][1], cHX[i], 0, 0, 0);
        cHY[i] = __builtin_amdgcn_mfma_f32_16x16x32_bf16(ya1, b1[i][1], cHY[i], 0, 0, 0);
      }
#pragma unroll
      for (int i = 0; i < 3; ++i) {
        cLX[i] = __builtin_amdgcn_mfma_f32_16x16x32_bf16(xl1, b1[i][1], cLX[i], 0, 0, 0);
        cLY[i] = __builtin_amdgcn_mfma_f32_16x16x32_bf16(yl1, b1[i][1], cLY[i], 0, 0, 0);
      }
    }
    if (lq < 2) {
#pragma unroll
      for (int i = 0; i < 3; ++i)
#pragma unroll
        for (int r = 0; r < 4; ++r) {
          gsX[lq * 4 + r][w * 48 + i * 16 + lj] = cHX[i][r] + cLX[i][r];
          gsY[lq * 4 + r][w * 48 + i * 16 + lj] = cHY[i][r] + cLY[i][r];
        }
    }
    if (p > 0 && fcXth) {
      float a = fcbr;
#pragma unroll
      for (int uq = 0; uq < 12; ++uq) {
        f32x4 hv = *(const f32x4*)&h2fX[fn][uq * 4];
        f32x4 wv = *(const f32x4*)&fcws[fk * 48 + uq * 4];
        a += hv[0] * wv[0] + hv[1] * wv[1] + hv[2] * wv[2] + hv[3] * wv[3];
      }
      logitX[fk][fn] = a;
    }
    if (p > 0 && fcYth) {
      float a = fcbr;
#pragma unroll
      for (int uq = 0; uq < 12; ++uq) {
        f32x4 hv = *(const f32x4*)&h2fY[fn][uq * 4];
        f32x4 wv = *(const f32x4*)&fcws[fk * 48 + uq * 4];
        a += hv[0] * wv[0] + hv[1] * wv[1] + hv[2] * wv[2] + hv[3] * wv[3];
      }
      logitY[fk][fn] = a;
    }
    lds_barrier();
    // ======== PHASE B: L1 activations X+Y | softmax p-1 X+Y ========
    {
      const int n = tn0, u = tu0;
      {
        const float ig = gsX[n][u], fg = gsX[n][48 + u];
        const float gg = gsX[n][96 + u], og = gsX[n][144 + u];
        const float cc = sigf(fg) * c1X[0] + sigf(ig) * tanh_f(gg);
        c1X[0] = cc;
        const float h = sigf(og) * tanh_f(cc);
        unsigned short hb, lb; hsplit(h, hb, lb);
        hhX[n][u] = (short)hb; hlX[n][u] = (short)lb;
      }
      {
        const float ig = gsY[n][u], fg = gsY[n][48 + u];
        const float gg = gsY[n][96 + u], og = gsY[n][144 + u];
        const float cc = sigf(fg) * c1Y[0] + sigf(ig) * tanh_f(gg);
        c1Y[0] = cc;
        const float h = sigf(og) * tanh_f(cc);
        unsigned short hb, lb; hsplit(h, hb, lb);
        hhY[n][u] = (short)hb; hlY[n][u] = (short)lb;
      }
    }
    if (tid < 128) {
      const int n = tn1, u = tu1;
      {
        const float ig = gsX[n][u], fg = gsX[n][48 + u];
        const float gg = gsX[n][96 + u], og = gsX[n][144 + u];
        const float cc = sigf(fg) * c1X[1] + sigf(ig) * tanh_f(gg);
        c1X[1] = cc;
        const float h = sigf(og) * tanh_f(cc);
        unsigned short hb, lb; hsplit(h, hb, lb);
        hhX[n][u] = (short)hb; hlX[n][u] = (short)lb;
      }
      {
        const float ig = gsY[n][u], fg = gsY[n][48 + u];
        const float gg = gsY[n][96 + u], og = gsY[n][144 + u];
        const float cc = sigf(fg) * c1Y[1] + sigf(ig) * tanh_f(gg);
        c1Y[1] = cc;
        const float h = sigf(og) * tanh_f(cc);
        unsigned short hb, lb; hsplit(h, hb, lb);
        hhY[n][u] = (short)hb; hlY[n][u] = (short)lb;
      }
    }
    if (p > 0 && smXth) {
      const int n = smn;
      const float l0 = logitX[0][n], l1 = logitX[1][n], l2 = logitX[2][n],
                  l3 = logitX[3][n], l4 = logitX[4][n];
      const float m = fmaxf(fmaxf(fmaxf(l0, l1), fmaxf(l2, l3)), l4);
      const float e0 = __expf(l0 - m), e1 = __expf(l1 - m), e2 = __expf(l2 - m),
                  e3 = __expf(l3 - m), e4 = __expf(l4 - m);
      const float rs = __builtin_amdgcn_rcpf(e0 + e1 + e2 + e3 + e4);
      probX[0][n] = e0 * rs; probX[1][n] = e1 * rs; probX[2][n] = e2 * rs;
      probX[3][n] = e3 * rs; probX[4][n] = e4 * rs;
    }
    if (p > 0 && smYth) {
      const int n = smn;
      const float l0 = logitY[0][n], l1 = logitY[1][n], l2 = logitY[2][n],
                  l3 = logitY[3][n], l4 = logitY[4][n];
      const float m = fmaxf(fmaxf(fmaxf(l0, l1), fmaxf(l2, l3)), l4);
      const float e0 = __expf(l0 - m), e1 = __expf(l1 - m), e2 = __expf(l2 - m),
                  e3 = __expf(l3 - m), e4 = __expf(l4 - m);
      const float rs = __builtin_amdgcn_rcpf(e0 + e1 + e2 + e3 + e4);
      probY[0][n] = e0 * rs; probY[1][n] = e1 * rs; probY[2][n] = e2 * rs;
      probY[3][n] = e3 * rs; probY[4][n] = e4 * rs;
    }
    lds_barrier();
    // ======== PHASE C: L2 MFMA X+Y | store p-1 X+Y ========
    f32x4 dHX[3], dLX[3], dHY[3], dLY[3];
#pragma unroll
    for (int i = 0; i < 3; ++i) {
      dHX[i][0] = bias2r[i]; dHX[i][1] = bias2r[i];
      dHX[i][2] = bias2r[i]; dHX[i][3] = bias2r[i];
      dHY[i][0] = bias2r[i]; dHY[i][1] = bias2r[i];
      dHY[i][2] = bias2r[i]; dHY[i][3] = bias2r[i];
      dLX[i][0] = 0.f; dLX[i][1] = 0.f; dLX[i][2] = 0.f; dLX[i][3] = 0.f;
      dLY[i][0] = 0.f; dLY[i][1] = 0.f; dLY[i][2] = 0.f; dLY[i][3] = 0.f;
    }
    {
      const short* hrX = &hhX[lj][0];
      const short* lrX = &hlX[lj][0];
      const short* hrY = &hhY[lj][0];
      const short* lrY = &hlY[lj][0];
      bf16x8 xa0 = *(const bf16x8*)(hrX + lq * 8);
      bf16x8 xa1 = *(const bf16x8*)(hrX + 32 + lq * 8);
      bf16x8 xa2 = *(const bf16x8*)(hrX + 64 + lq * 8);
      bf16x8 xq0 = *(const bf16x8*)(lrX + lq * 8);
      bf16x8 xq1 = *(const bf16x8*)(lrX + 32 + lq * 8);
      bf16x8 xq2 = *(const bf16x8*)(lrX + 64 + lq * 8);
      bf16x8 ya0 = *(const bf16x8*)(hrY + lq * 8);
      bf16x8 ya1 = *(const bf16x8*)(hrY + 32 + lq * 8);
      bf16x8 ya2 = *(const bf16x8*)(hrY + 64 + lq * 8);
      bf16x8 yq0 = *(const bf16x8*)(lrY + lq * 8);
      bf16x8 yq1 = *(const bf16x8*)(lrY + 32 + lq * 8);
      bf16x8 yq2 = *(const bf16x8*)(lrY + 64 + lq * 8);
#pragma unroll
      for (int i = 0; i < 3; ++i) {
        dHX[i] = __builtin_amdgcn_mfma_f32_16x16x32_bf16(xa0, b2f[i][0], dHX[i], 0, 0, 0);
        dHY[i] = __builtin_amdgcn_mfma_f32_16x16x32_bf16(ya0, b2f[i][0], dHY[i], 0, 0, 0);
      }
#pragma unroll
      for (int i = 0; i < 3; ++i) {
        dLX[i] = __builtin_amdgcn_mfma_f32_16x16x32_bf16(xq0, b2f[i][0], dLX[i], 0, 0, 0);
        dLY[i] = __builtin_amdgcn_mfma_f32_16x16x32_bf16(yq0, b2f[i][0], dLY[i], 0, 0, 0);
      }
#pragma unroll
      for (int i = 0; i < 3; ++i) {
        dHX[i] = __builtin_amdgcn_mfma_f32_16x16x32_bf16(xa1, b2f[i][1], dHX[i], 0, 0, 0);
        dHY[i] = __builtin_amdgcn_mfma_f32_16x16x32_bf16(ya1, b2f[i][1], dHY[i], 0, 0, 0);
      }
#pragma unroll
      for (int i = 0; i < 3; ++i) {
        dLX[i] = __builtin_amdgcn_mfma_f32_16x16x32_bf16(xq1, b2f[i][1], dLX[i], 0, 0, 0);
        dLY[i] = __builtin_amdgcn_mfma_f32_16x16x32_bf16(yq1, b2f[i][1], dLY[i], 0, 0, 0);
      }
#pragma unroll
      for (int i = 0; i < 3; ++i) {
        dHX[i] = __builtin_amdgcn_mfma_f32_16x16x32_bf16(xa2, b2f[i][2], dHX[i], 0, 0, 0);
        dHY[i] = __builtin_amdgcn_mfma_f32_16x16x32_bf16(ya2, b2f[i][2], dHY[i], 0, 0, 0);
      }
#pragma unroll
      for (int i = 0; i < 3; ++i) {
        dLX[i] = __builtin_amdgcn_mfma_f32_16x16x32_bf16(xq2, b2f[i][2], dLX[i], 0, 0, 0);
        dLY[i] = __builtin_amdgcn_mfma_f32_16x16x32_bf16(yq2, b2f[i][2], dLY[i], 0, 0, 0);
      }
    }
    if (lq < 2) {
#pragma unroll
      for (int i = 0; i < 3; ++i)
#pragma unroll
        for (int r = 0; r < 4; ++r) {
          gsX[lq * 4 + r][w * 48 + i * 16 + lj] = dHX[i][r] + dLX[i][r];
          gsY[lq * 4 + r][w * 48 + i * 16 + lj] = dHY[i][r] + dLY[i][r];
        }
    }
    if (p > 0 && stXth) {
      out[(((size_t)b * P_ + (p - 1)) * 5 + sk) * T_ + t0 + sn] = probX[sk][sn];
    }
    if (p > 0 && stYth) {
      out[(((size_t)b * P_ + (p - 1)) * 5 + sk) * T_ + t0 + 8 + sn] = probY[sk][sn];
    }
    lds_barrier();
    // ======== PHASE D: L2 activations X+Y ========
    {
      const int n = tn0, u = tu0;
      {
        const float ig = gsX[n][u], fg = gsX[n][48 + u];
        const float gg = gsX[n][96 + u], og = gsX[n][144 + u];
        const float cc = sigf(fg) * c2X[0] + sigf(ig) * tanh_f(gg);
        c2X[0] = cc;
        const float h = sigf(og) * tanh_f(cc);
        unsigned short hb, lb; hsplit(h, hb, lb);
        hhX[n][48 + u] = (short)hb; hlX[n][48 + u] = (short)lb;
        h2fX[n][u] = h;
      }
      {
        const float ig = gsY[n][u], fg = gsY[n][48 + u];
        const float gg = gsY[n][96 + u], og = gsY[n][144 + u];
        const float cc = sigf(fg) * c2Y[0] + sigf(ig) * tanh_f(gg);
        c2Y[0] = cc;
        const float h = sigf(og) * tanh_f(cc);
        unsigned short hb, lb; hsplit(h, hb, lb);
        hhY[n][48 + u] = (short)hb; hlY[n][48 + u] = (short)lb;
        h2fY[n][u] = h;
      }
    }
    if (tid < 128) {
      const int n = tn1, u = tu1;
      {
        const float ig = gsX[n][u], fg = gsX[n][48 + u];
        const float gg = gsX[n][96 + u], og = gsX[n][144 + u];
        const float cc = sigf(fg) * c2X[1] + sigf(ig) * tanh_f(gg);
        c2X[1] = cc;
        const float h = sigf(og) * tanh_f(cc);
        unsigned short hb, lb; hsplit(h, hb, lb);
        hhX[n][48 + u] = (short)hb; hlX[n][48 + u] = (short)lb;
        h2fX[n][u] = h;
      }
      {
        const float ig = gsY[n][u], fg = gsY[n][48 + u];
        const float gg = gsY[n][96 + u], og = gsY[n][144 + u];
        const float cc = sigf(fg) * c2Y[1] + sigf(ig) * tanh_f(gg);
        c2Y[1] = cc;
        const float h = sigf(og) * tanh_f(cc);
        unsigned short hb, lb; hsplit(h, hb, lb);
        hhY[n][48 + u] = (short)hb; hlY[n][48 + u] = (short)lb;
        h2fY[n][u] = h;
      }
    }
    lds_barrier();
  }
  // ---- epilogue: logits(P-1), softmax, store(P-1) for both groups ----
  if (fcXth) {
    float a = fcbr;
#pragma unroll
    for (int uq = 0; uq < 12; ++uq) {
      f32x4 hv = *(const f32x4*)&h2fX[fn][uq * 4];
      f32x4 wv = *(const f32x4*)&fcws[fk * 48 + uq * 4];
      a += hv[0] * wv[0] + hv[1] * wv[1] + hv[2] * wv[2] + hv[3] * wv[3];
    }
    logitX[fk][fn] = a;
  }
  if (fcYth) {
    float a = fcbr;
#pragma unroll
    for (int uq = 0; uq < 12; ++uq) {
      f32x4 hv = *(const f32x4*)&h2fY[fn][uq * 4];
      f32x4 wv = *(const f32x4*)&fcws[fk * 48 + uq * 4];
      a += hv[0] * wv[0] + hv[1] * wv[1] + hv[2] * wv[2] + hv[3] * wv[3];
    }
    logitY[fk][fn] = a;
  }
  lds_barrier();
  if (smXth) {
    const int n = smn;
    const float l0 = logitX[0][n], l1 = logitX[1][n], l2 = logitX[2][n],
                l3 = logitX[3][n], l4 = logitX[4][n];
    const float m = fmaxf(fmaxf(fmaxf(l0, l1), fmaxf(l2, l3)), l4);
    const float e0 = __expf(l0 - m), e1 = __expf(l1 - m), e2 = __expf(l2 - m),
                e3 = __expf(l3 - m), e4 = __expf(l4 - m);
    const float rs = __builtin_amdgcn_rcpf(e0 + e1 + e2 + e3 + e4);
    probX[0][n] = e0 * rs; probX[1][n] = e1 * rs; probX[2][n] = e2 * rs;
    probX[3][n] = e3 * rs; probX[4][n] = e4 * rs;
  }
  if (smYth) {
    const int n = smn;
    const float l0 = logitY[0][n], l1 = logitY[1][n], l2 = logitY[2][n],
                l3 = logitY[3][n], l4 = logitY[4][n];
    const float m = fmaxf(fmaxf(fmaxf(l0, l1), fmaxf(l2, l3)), l4);
    const float e0 = __expf(l0 - m), e1 = __expf(l1 - m), e2 = __expf(l2 - m),
                e3 = __expf(l3 - m), e4 = __expf(l4 - m);
    const float rs = __builtin_amdgcn_rcpf(e0 + e1 + e2 + e3 + e4);
    probY[0][n] = e0 * rs; probY[1][n] = e1 * rs; probY[2][n] = e2 * rs;
    probY[3][n] = e3 * rs; probY[4][n] = e4 * rs;
  }
  lds_barrier();
  if (stXth) {
    out[(((size_t)b * P_ + (P_ - 1)) * 5 + sk) * T_ + t0 + sn] = probX[sk][sn];
  }
  if (stYth) {
    out[(((size_t)b * P_ + (P_ - 1)) * 5 + sk) * T_ + t0 + 8 + sn] = probY[sk][sn];
  }
}

extern "C" void kernel_launch(void* const* d_in, const int* in_sizes, int n_in,
                              void* d_out, int out_size, void* d_ws, size_t ws_size,
                              hipStream_t stream) {
  const float* pf   = (const float*)d_in[0];
  const float* pc   = (const float*)d_in[1];
  const float* fc1w = (const float*)d_in[2];
  const float* fc1b = (const float*)d_in[3];
  const float* fc2w = (const float*)d_in[4];
  const float* fc2b = (const float*)d_in[5];
  const float* fc3w = (const float*)d_in[6];
  const float* fc3b = (const float*)d_in[7];
  const float* wih1 = (const float*)d_in[8];
  const float* whh1 = (const float*)d_in[9];
  const float* bih1 = (const float*)d_in[10];
  const float* bhh1 = (const float*)d_in[11];
  const float* wih2 = (const float*)d_in[12];
  const float* whh2 = (const float*)d_in[13];
  const float* bih2 = (const float*)d_in[14];
  const float* bhh2 = (const float*)d_in[15];
  const float* fcw  = (const float*)d_in[16];
  const float* fcb  = (const float*)d_in[17];
  float* out = (float*)d_out;

  char* wsp = (char*)d_ws;
  float* ctxg = (float*)wsp;                                     // 1,081,344 B
  const size_t CTXG_BYTES = (size_t)B_ * P_ * G_ * sizeof(float);
  f16x8* wfrag = (f16x8*)(wsp + CTXG_BYTES);                     // 73,728 B
  const size_t WFRAG_BYTES = (size_t)12 * 6 * 64 * 16;
  unsigned short* xg2 = (unsigned short*)(wsp + CTXG_BYTES + WFRAG_BYTES);  // ~138.5 MB

  ctx_kernel<<<22, 64, 0, stream>>>(pc, fc1w, fc1b, fc2w, fc2b, fc3w, fc3b,
                                    wih1, bih1, bhh1, ctxg);
  wfrag_kernel<<<18, 256, 0, stream>>>(wih1, wfrag);
  gemm_mfma<<<B_ * P_ * 2, 256, 0, stream>>>(pf, wfrag, ctxg, xg2);
  scan_mfma<<<N_ / 16, 256, 0, stream>>>(xg2, whh1, wih2, whh2,
                                         bih2, bhh2, fcw, fcb, out);
}

// Round 13
// 397.162 us; speedup vs baseline: 1.3236x; 1.3236x over previous
//
#include <hip/hip_runtime.h>
#include <hip/hip_bf16.h>
#include <cstdint>

#define P_ 88   // pitches (sequence length of the scan)
#define B_ 16   // batch
#define T_ 256  // timesteps (folded into batch N)
#define H_ 188  // per-pitch features
#define G_ 192  // 4*48 gates; also LSTM1 input size (188 feat + 4 ctx)
#define U_ 48   // LSTM units
#define N_ 4096 // B_*T_

typedef __attribute__((ext_vector_type(8))) short bf16x8;
typedef __attribute__((ext_vector_type(8))) _Float16 f16x8;
typedef __attribute__((ext_vector_type(4))) float f32x4;

__device__ __forceinline__ float sigf(float x) {
  return __builtin_amdgcn_rcpf(1.0f + __expf(-x));
}
__device__ __forceinline__ float tanh_f(float x) {
  return 1.0f - 2.0f * __builtin_amdgcn_rcpf(1.0f + __expf(2.0f * x));
}
__device__ __forceinline__ float hs2f(unsigned short s) {
  union { unsigned short u; _Float16 h; } x;
  x.u = s;
  return (float)x.h;
}
__device__ __forceinline__ unsigned short f2hs(float v) {
  union { _Float16 h; unsigned short s; } x;
  x.h = (_Float16)v;
  return x.s;
}

// Relaxed workgroup barrier: waits only on LDS ops (lgkmcnt), NOT vmcnt.
__device__ __forceinline__ void lds_barrier() {
  asm volatile("s_waitcnt lgkmcnt(0)\n\ts_barrier" ::: "memory");
}

// ---------------------------------------------------------------------------
// Kernel 1: context MLP -> per-(b,p) gate bias vector
// ---------------------------------------------------------------------------
__global__ void ctx_kernel(const float* __restrict__ pc,
                           const float* __restrict__ fc1w, const float* __restrict__ fc1b,
                           const float* __restrict__ fc2w, const float* __restrict__ fc2b,
                           const float* __restrict__ fc3w, const float* __restrict__ fc3b,
                           const float* __restrict__ wih1,
                           const float* __restrict__ bih1, const float* __restrict__ bhh1,
                           float* __restrict__ ctxg) {
  int bp = blockIdx.x * 64 + threadIdx.x;
  if (bp >= B_ * P_) return;
  float p0 = pc[bp * 3 + 0], p1 = pc[bp * 3 + 1], p2 = pc[bp * 3 + 2];
  float x1[16], x2[16];
#pragma unroll
  for (int jj = 0; jj < 16; ++jj)
    x1[jj] = fmaxf(0.f, fc1w[jj * 3 + 0] * p0 + fc1w[jj * 3 + 1] * p1 + fc1w[jj * 3 + 2] * p2 + fc1b[jj]);
#pragma unroll
  for (int jj = 0; jj < 16; ++jj) {
    float s = fc2b[jj];
#pragma unroll
    for (int i = 0; i < 16; ++i) s += fc2w[jj * 16 + i] * x1[i];
    x2[jj] = fmaxf(0.f, s);
  }
  float ce[4];
#pragma unroll
  for (int jj = 0; jj < 4; ++jj) {
    float s = fc3b[jj];
#pragma unroll
    for (int i = 0; i < 16; ++i) s += fc3w[jj * 16 + i] * x2[i];
    ce[jj] = s;
  }
  float* op = ctxg + (size_t)bp * G_;
  for (int g = 0; g < G_; ++g) {
    const float* wr = wih1 + (size_t)g * G_ + H_;
    op[g] = bih1[g] + bhh1[g] + ce[0] * wr[0] + ce[1] * wr[1] + ce[2] * wr[2] + ce[3] * wr[3];
  }
}

// ---------------------------------------------------------------------------
// Kernel 1b: pack wih1 feature columns into f16 MFMA B-fragment order.
// ---------------------------------------------------------------------------
__global__ __launch_bounds__(256) void wfrag_kernel(const float* __restrict__ wih1,
                                                    f16x8* __restrict__ wfrag) {
  const int idx = blockIdx.x * 256 + threadIdx.x;
  if (idx >= 12 * 6 * 64) return;
  const int l = idx & 63;
  const int kc = (idx >> 6) % 6;
  const int j = idx / 384;
  const int g = j * 16 + (l & 15);
  const int k0 = kc * 32 + (l >> 4) * 8;
  f16x8 v;
#pragma unroll
  for (int e = 0; e < 8; ++e) {
    const int k = k0 + e;
    const float wv = (k < H_) ? wih1[(size_t)g * G_ + k] : 0.f;
    v[e] = (_Float16)wv;
  }
  wfrag[idx] = v;
}

// ---------------------------------------------------------------------------
// Kernel 2: MFMA GEMM with LDS-staged A and LDS-repacked stores (round 10).
// ---------------------------------------------------------------------------
__global__ __launch_bounds__(256, 3) void gemm_mfma(const float* __restrict__ pf,
                                                    const f16x8* __restrict__ wfrag,
                                                    const float* __restrict__ ctxg,
                                                    unsigned short* __restrict__ xg2) {
  const int bp = blockIdx.x >> 1, tb = blockIdx.x & 1;
  const int p = bp % P_, b = bp / P_;
  const int tid = threadIdx.x;
  const int w = tid >> 6, l = tid & 63;
  const int lj = l & 15, lq = l >> 4;

  __shared__ __align__(16) char ldsraw[49152];
  _Float16(*Ahi)[34] = (_Float16(*)[34])ldsraw;
  _Float16(*Alo)[34] = (_Float16(*)[34])(ldsraw + 8704);

  float cg[12];
#pragma unroll
  for (int jn = 0; jn < 12; ++jn)
    cg[jn] = ctxg[(size_t)bp * G_ + jn * 16 + lj];

  f32x4 acc[2][12];
#pragma unroll
  for (int mt = 0; mt < 2; ++mt)
#pragma unroll
    for (int jn = 0; jn < 12; ++jn)
#pragma unroll
      for (int r = 0; r < 4; ++r) acc[mt][jn][r] = 0.f;

  const float* Ab = pf + (size_t)bp * H_ * T_ + tb * 128;
  const int kl = tid >> 5;
  const int t4 = (tid & 31) * 4;

  for (int kc = 0; kc < 6; ++kc) {
    __syncthreads();
#pragma unroll
    for (int rr = 0; rr < 4; ++rr) {
      const int kk = rr * 8 + kl;
      const int kg = kc * 32 + kk;
      float a0 = 0.f, a1 = 0.f, a2 = 0.f, a3 = 0.f;
      if (kg < H_) {
        const float4 v = *(const float4*)(Ab + (size_t)kg * T_ + t4);
        a0 = v.x; a1 = v.y; a2 = v.z; a3 = v.w;
      }
      const _Float16 h0 = (_Float16)a0, h1 = (_Float16)a1;
      const _Float16 h2 = (_Float16)a2, h3 = (_Float16)a3;
      Ahi[t4 + 0][kk] = h0; Alo[t4 + 0][kk] = (_Float16)(a0 - (float)h0);
      Ahi[t4 + 1][kk] = h1; Alo[t4 + 1][kk] = (_Float16)(a1 - (float)h1);
      Ahi[t4 + 2][kk] = h2; Alo[t4 + 2][kk] = (_Float16)(a2 - (float)h2);
      Ahi[t4 + 3][kk] = h3; Alo[t4 + 3][kk] = (_Float16)(a3 - (float)h3);
    }
    __syncthreads();
    const int trow = w * 32;
    const f16x8 ahi0 = *(const f16x8*)&Ahi[trow + lj][lq * 8];
    const f16x8 ahi1 = *(const f16x8*)&Ahi[trow + 16 + lj][lq * 8];
    const f16x8 alo0 = *(const f16x8*)&Alo[trow + lj][lq * 8];
    const f16x8 alo1 = *(const f16x8*)&Alo[trow + 16 + lj][lq * 8];
#pragma unroll
    for (int jn = 0; jn < 12; ++jn) {
      const f16x8 wf = wfrag[(jn * 6 + kc) * 64 + l];
      acc[0][jn] = __builtin_amdgcn_mfma_f32_16x16x32_f16(ahi0, wf, acc[0][jn], 0, 0, 0);
      acc[1][jn] = __builtin_amdgcn_mfma_f32_16x16x32_f16(ahi1, wf, acc[1][jn], 0, 0, 0);
      acc[0][jn] = __builtin_amdgcn_mfma_f32_16x16x32_f16(alo0, wf, acc[0][jn], 0, 0, 0);
      acc[1][jn] = __builtin_amdgcn_mfma_f32_16x16x32_f16(alo1, wf, acc[1][jn], 0, 0, 0);
    }
  }
  __syncthreads();

  unsigned short* Cst = (unsigned short*)ldsraw + w * 6144;
#pragma unroll
  for (int mt = 0; mt < 2; ++mt)
#pragma unroll
    for (int jn = 0; jn < 12; ++jn)
#pragma unroll
      for (int r = 0; r < 4; ++r)
        Cst[mt * 3072 + jn * 256 + r * 64 + l] = f2hs(acc[mt][jn][r] + cg[jn]);
  const int nb0 = b * 16 + tb * 8 + w * 2;
  unsigned short* gb = xg2 + ((size_t)p * 256 + nb0) * 3072;
#pragma unroll
  for (int rr = 0; rr < 12; ++rr) {
    const uint4 v = *(const uint4*)(Cst + rr * 512 + l * 8);
    *(uint4*)(gb + rr * 512 + l * 8) = v;
  }
}

// ---------------------------------------------------------------------------
// Kernel 3: MFMA persistent scan, 2-PHASE PIPELINED + f16 h.
// 512 blocks (2/CU) x 256 threads, NB=8. Per iteration p (= -1..87):
//   M: L2-MFMA(p) + L1-MFMA(p+1) off SHARED h fragments (3 ds_read_b128),
//      + fc-logits(p-1) + store(p-2); barrier.
//   V: act2(p) + act1(p+1) (4 independent tasks/thread) + softmax(p-1);
//      barrier.
// h single-buffered f16 (reads all in M, writes all in V). gs1/gs2 separate.
// ---------------------------------------------------------------------------
__global__ __launch_bounds__(256, 2) void scan_mfma(
    const unsigned short* __restrict__ xg2,
    const float* __restrict__ whh1, const float* __restrict__ wih2,
    const float* __restrict__ whh2, const float* __restrict__ bih2,
    const float* __restrict__ bhh2, const float* __restrict__ fcw,
    const float* __restrict__ fcb, float* __restrict__ out) {
  __shared__ __align__(16) _Float16 h12[16][104];  // cols 0-47 h1, 48-95 h2
  __shared__ __align__(16) float gs1[8][196];      // L1 gate staging
  __shared__ __align__(16) float gs2[8][196];      // L2 gate staging
  __shared__ __align__(16) float h2f[8][52];       // h2 fp32 for fc_states
  __shared__ __align__(16) float fcws[5 * 48];
  __shared__ float logit_s[5][8];
  __shared__ float prob_s[5][8];

  const int tid = threadIdx.x;
  const int w = tid >> 6;
  const int l = tid & 63;
  const int lj = l & 15;
  const int lq = l >> 4;
  const int grp = blockIdx.x >> 1;
  const int half = blockIdx.x & 1;
  const int n0 = blockIdx.x * 8;
  const int b = n0 >> 8, t0 = n0 & 255;

  // ---- persistent weight B-fragments, f16 ----
  f16x8 b1[3][2];
  f16x8 b2f[3][3];
  float bias2r[3];
#pragma unroll
  for (int i = 0; i < 3; ++i) {
    const int j = w * 48 + i * 16 + lj;
    bias2r[i] = bih2[j] + bhh2[j];
#pragma unroll
    for (int kc = 0; kc < 2; ++kc)
#pragma unroll
      for (int e = 0; e < 8; ++e) {
        const int u = kc * 32 + lq * 8 + e;
        b1[i][kc][e] = (u < U_) ? (_Float16)whh1[j * U_ + u] : (_Float16)0.f;
      }
#pragma unroll
    for (int kc = 0; kc < 3; ++kc)
#pragma unroll
      for (int e = 0; e < 8; ++e) {
        const int k = kc * 32 + lq * 8 + e;
        b2f[i][kc][e] = (k < U_) ? (_Float16)wih2[j * U_ + k]
                                 : (_Float16)whh2[j * U_ + (k - U_)];
      }
  }

  for (int e = tid; e < 16 * 104 / 2; e += 256) ((unsigned int*)h12)[e] = 0u;
  for (int e = tid; e < 5 * U_; e += 256) fcws[e] = fcw[e];

  // activation tasks: 384 = 8n x 48u per layer; slot0 = tid, slot1 = 256+tid (tid<128)
  const int tn0 = tid / U_, tu0 = tid % U_;
  const int tn1 = (256 + tid) / U_, tu1 = (256 + tid) % U_;
  const bool has2 = (tid < 128);
  float c1s[2] = {0.f, 0.f}, c2s[2] = {0.f, 0.f};

  // aux roles (as r10): fc tid 0-39, store 96-135, softmax 192-199
  const bool fcth = tid < 40;
  const int fk = tid >> 3, fn = tid & 7;
  const float fcbr = fcth ? fcb[fk] : 0.f;
  const bool stth = tid >= 96 && tid < 136;
  const int sk = (tid - 96) >> 3, sn = (tid - 96) & 7;
  const bool smth = tid >= 192 && tid < 200;
  const int smn = tid - 192;

  // xg prefetch for step 0 (lanes lq<2 hold rows half*8 + lq*4+r)
  unsigned short xp[12];
  {
    const size_t pb = (size_t)grp * 3072;
#pragma unroll
    for (int i = 0; i < 3; ++i)
#pragma unroll
      for (int r = 0; r < 4; ++r)
        xp[i * 4 + r] = (lq < 2)
            ? xg2[pb + (size_t)((w * 3 + i) * 256 + r * 64 + (half * 2 + lq) * 16 + lj)]
            : (unsigned short)0;
  }
  lds_barrier();

  for (int p = -1; p < P_; ++p) {
    // ================= M: MFMA phase =================
    // shared h fragments (h1 | h2 concatenated; zero-initialized pre-loop)
    const _Float16* hr = &h12[lj][0];
    const f16x8 f0 = *(const f16x8*)(hr + lq * 8);
    const f16x8 f1 = *(const f16x8*)(hr + 32 + lq * 8);
    const f16x8 f2 = *(const f16x8*)(hr + 64 + lq * 8);
    if (p >= 0) {  // L2(p): K=96 over [h1(p); h2(p-1)]
      f32x4 dH[3];
#pragma unroll
      for (int i = 0; i < 3; ++i) {
        dH[i][0] = bias2r[i]; dH[i][1] = bias2r[i];
        dH[i][2] = bias2r[i]; dH[i][3] = bias2r[i];
      }
#pragma unroll
      for (int i = 0; i < 3; ++i)
        dH[i] = __builtin_amdgcn_mfma_f32_16x16x32_f16(f0, b2f[i][0], dH[i], 0, 0, 0);
#pragma unroll
      for (int i = 0; i < 3; ++i)
        dH[i] = __builtin_amdgcn_mfma_f32_16x16x32_f16(f1, b2f[i][1], dH[i], 0, 0, 0);
#pragma unroll
      for (int i = 0; i < 3; ++i)
        dH[i] = __builtin_amdgcn_mfma_f32_16x16x32_f16(f2, b2f[i][2], dH[i], 0, 0, 0);
      if (lq < 2) {
#pragma unroll
        for (int i = 0; i < 3; ++i)
#pragma unroll
          for (int r = 0; r < 4; ++r)
            gs2[lq * 4 + r][w * 48 + i * 16 + lj] = dH[i][r];
      }
    }
    if (p >= 1 && fcth) {  // fc logits for step p-1 (h2f written in V(p-1))
      float a = fcbr;
#pragma unroll
      for (int uq = 0; uq < 12; ++uq) {
        f32x4 hv = *(const f32x4*)&h2f[fn][uq * 4];
        f32x4 wv = *(const f32x4*)&fcws[fk * 48 + uq * 4];
        a += hv[0] * wv[0] + hv[1] * wv[1] + hv[2] * wv[2] + hv[3] * wv[3];
      }
      logit_s[fk][fn] = a;
    }
    if (p >= 2 && stth) {  // store probs of step p-2 (softmax'd in V(p-1))
      out[(((size_t)b * P_ + (p - 2)) * 5 + sk) * T_ + t0 + sn] = prob_s[sk][sn];
    }
    __builtin_amdgcn_sched_barrier(0);  // keep dH retired before cH allocates
    if (p < P_ - 1) {  // L1(p+1): C init = xg(p+1), K=48 (pad 64) over h1(p)
      f32x4 cH[3];
#pragma unroll
      for (int i = 0; i < 3; ++i)
#pragma unroll
        for (int r = 0; r < 4; ++r) cH[i][r] = hs2f(xp[i * 4 + r]);
      if (p < P_ - 2) {  // prefetch xg(p+2); stays in flight across barriers
        const size_t pb = (size_t)((p + 2) * 256 + grp) * 3072;
#pragma unroll
        for (int i = 0; i < 3; ++i)
#pragma unroll
          for (int r = 0; r < 4; ++r)
            xp[i * 4 + r] = (lq < 2)
                ? xg2[pb + (size_t)((w * 3 + i) * 256 + r * 64 + (half * 2 + lq) * 16 + lj)]
                : (unsigned short)0;
      }
#pragma unroll
      for (int i = 0; i < 3; ++i)
        cH[i] = __builtin_amdgcn_mfma_f32_16x16x32_f16(f0, b1[i][0], cH[i], 0, 0, 0);
#pragma unroll
      for (int i = 0; i < 3; ++i)
        cH[i] = __builtin_amdgcn_mfma_f32_16x16x32_f16(f1, b1[i][1], cH[i], 0, 0, 0);
      if (lq < 2) {
#pragma unroll
        for (int i = 0; i < 3; ++i)
#pragma unroll
          for (int r = 0; r < 4; ++r)
            gs1[lq * 4 + r][w * 48 + i * 16 + lj] = cH[i][r];
      }
    }
    lds_barrier();
    // ================= V: activation phase =================
    if (p >= 0) {  // act2(p) -> h2(p), h2f(p)
      {
        const int n = tn0, u = tu0;
        const float ig = gs2[n][u], fg = gs2[n][48 + u];
        const float gg = gs2[n][96 + u], og = gs2[n][144 + u];
        const float cc = sigf(fg) * c2s[0] + sigf(ig) * tanh_f(gg);
        c2s[0] = cc;
        const float h = sigf(og) * tanh_f(cc);
        h12[n][48 + u] = (_Float16)h;
        h2f[n][u] = h;
      }
      if (has2) {
        const int n = tn1, u = tu1;
        const float ig = gs2[n][u], fg = gs2[n][48 + u];
        const float gg = gs2[n][96 + u], og = gs2[n][144 + u];
        const float cc = sigf(fg) * c2s[1] + sigf(ig) * tanh_f(gg);
        c2s[1] = cc;
        const float h = sigf(og) * tanh_f(cc);
        h12[n][48 + u] = (_Float16)h;
        h2f[n][u] = h;
      }
    }
    if (p < P_ - 1) {  // act1(p+1) -> h1(p+1)
      {
        const int n = tn0, u = tu0;
        const float ig = gs1[n][u], fg = gs1[n][48 + u];
        const float gg = gs1[n][96 + u], og = gs1[n][144 + u];
        const float cc = sigf(fg) * c1s[0] + sigf(ig) * tanh_f(gg);
        c1s[0] = cc;
        h12[n][u] = (_Float16)(sigf(og) * tanh_f(cc));
      }
      if (has2) {
        const int n = tn1, u = tu1;
        const float ig = gs1[n][u], fg = gs1[n][48 + u];
        const float gg = gs1[n][96 + u], og = gs1[n][144 + u];
        const float cc = sigf(fg) * c1s[1] + sigf(ig) * tanh_f(gg);
        c1s[1] = cc;
        h12[n][u] = (_Float16)(sigf(og) * tanh_f(cc));
      }
    }
    if (p >= 1 && smth) {  // softmax of step p-1 (logits from M(p))
      const int n = smn;
      const float l0 = logit_s[0][n], l1 = logit_s[1][n], l2 = logit_s[2][n],
                  l3 = logit_s[3][n], l4 = logit_s[4][n];
      const float m = fmaxf(fmaxf(fmaxf(l0, l1), fmaxf(l2, l3)), l4);
      const float e0 = __expf(l0 - m), e1 = __expf(l1 - m), e2 = __expf(l2 - m),
                  e3 = __expf(l3 - m), e4 = __expf(l4 - m);
      const float rs = __builtin_amdgcn_rcpf(e0 + e1 + e2 + e3 + e4);
      prob_s[0][n] = e0 * rs; prob_s[1][n] = e1 * rs; prob_s[2][n] = e2 * rs;
      prob_s[3][n] = e3 * rs; prob_s[4][n] = e4 * rs;
    }
    lds_barrier();
  }
  // ---- epilogue: fc(87) + store(86); softmax(87); store(87) ----
  if (fcth) {
    float a = fcbr;
#pragma unroll
    for (int uq = 0; uq < 12; ++uq) {
      f32x4 hv = *(const f32x4*)&h2f[fn][uq * 4];
      f32x4 wv = *(const f32x4*)&fcws[fk * 48 + uq * 4];
      a += hv[0] * wv[0] + hv[1] * wv[1] + hv[2] * wv[2] + hv[3] * wv[3];
    }
    logit_s[fk][fn] = a;
  }
  if (stth) {
    out[(((size_t)b * P_ + (P_ - 2)) * 5 + sk) * T_ + t0 + sn] = prob_s[sk][sn];
  }
  lds_barrier();
  if (smth) {
    const int n = smn;
    const float l0 = logit_s[0][n], l1 = logit_s[1][n], l2 = logit_s[2][n],
                l3 = logit_s[3][n], l4 = logit_s[4][n];
    const float m = fmaxf(fmaxf(fmaxf(l0, l1), fmaxf(l2, l3)), l4);
    const float e0 = __expf(l0 - m), e1 = __expf(l1 - m), e2 = __expf(l2 - m),
                e3 = __expf(l3 - m), e4 = __expf(l4 - m);
    const float rs = __builtin_amdgcn_rcpf(e0 + e1 + e2 + e3 + e4);
    prob_s[0][n] = e0 * rs; prob_s[1][n] = e1 * rs; prob_s[2][n] = e2 * rs;
    prob_s[3][n] = e3 * rs; prob_s[4][n] = e4 * rs;
  }
  lds_barrier();
  if (stth) {
    out[(((size_t)b * P_ + (P_ - 1)) * 5 + sk) * T_ + t0 + sn] = prob_s[sk][sn];
  }
}

extern "C" void kernel_launch(void* const* d_in, const int* in_sizes, int n_in,
                              void* d_out, int out_size, void* d_ws, size_t ws_size,
                              hipStream_t stream) {
  const float* pf   = (const float*)d_in[0];
  const float* pc   = (const float*)d_in[1];
  const float* fc1w = (const float*)d_in[2];
  const float* fc1b = (const float*)d_in[3];
  const float* fc2w = (const float*)d_in[4];
  const float* fc2b = (const float*)d_in[5];
  const float* fc3w = (const float*)d_in[6];
  const float* fc3b = (const float*)d_in[7];
  const float* wih1 = (const float*)d_in[8];
  const float* whh1 = (const float*)d_in[9];
  const float* bih1 = (const float*)d_in[10];
  const float* bhh1 = (const float*)d_in[11];
  const float* wih2 = (const float*)d_in[12];
  const float* whh2 = (const float*)d_in[13];
  const float* bih2 = (const float*)d_in[14];
  const float* bhh2 = (const float*)d_in[15];
  const float* fcw  = (const float*)d_in[16];
  const float* fcb  = (const float*)d_in[17];
  float* out = (float*)d_out;

  char* wsp = (char*)d_ws;
  float* ctxg = (float*)wsp;                                     // 1,081,344 B
  const size_t CTXG_BYTES = (size_t)B_ * P_ * G_ * sizeof(float);
  f16x8* wfrag = (f16x8*)(wsp + CTXG_BYTES);                     // 73,728 B
  const size_t WFRAG_BYTES = (size_t)12 * 6 * 64 * 16;
  unsigned short* xg2 = (unsigned short*)(wsp + CTXG_BYTES + WFRAG_BYTES);  // ~138.5 MB

  ctx_kernel<<<22, 64, 0, stream>>>(pc, fc1w, fc1b, fc2w, fc2b, fc3w, fc3b,
                                    wih1, bih1, bhh1, ctxg);
  wfrag_kernel<<<18, 256, 0, stream>>>(wih1, wfrag);
  gemm_mfma<<<B_ * P_ * 2, 256, 0, stream>>>(pf, wfrag, ctxg, xg2);
  scan_mfma<<<N_ / 8, 256, 0, stream>>>(xg2, whh1, wih2, whh2,
                                        bih2, bhh2, fcw, fcb, out);
}